// Round 2
// baseline (948.874 us; speedup 1.0000x reference)
//
#include <hip/hip_runtime.h>

// ---------------------------------------------------------------------------
// BlockSparseMoE: T=4096 tokens, HID=1024, FFN=4096, E=8, top-2, fp32 in/out.
// route (fp32) -> permute tokens into 128-aligned expert segments -> bf16 MFMA
// grouped GEMMs (16x16x32) with global_load_lds(16B) staging.
// Workspace-adaptive: FFN is processed in nc = FFN/FC chunks so that
//   meta(144KB) + xbf(8MB) + 3 * [NE*FC*HID*2] + CAP*FC*2  <= ws_size.
// Per chunk: transpose w1/w3/w2 chunk to bf16 [n][k], GEMM1 -> h chunk,
// GEMM2 accumulates into out via atomicAdd (chunk-safe).
// ---------------------------------------------------------------------------

#define NTOK 4096
#define HID  1024
#define FFN  4096
#define NE   8
#define TM   128
#define CAP  9216   // max padded slots: 64*128 + 7*128 = 9088 < 9216
#define MAXT 72     // max m-tiles: 64 + 7 = 71 < 72

typedef __bf16 bf16x8 __attribute__((ext_vector_type(8)));
typedef float  f32x4  __attribute__((ext_vector_type(4)));

typedef __attribute__((address_space(3))) unsigned int       lds_uint;
typedef const __attribute__((address_space(1))) unsigned int glob_uint;

__device__ __forceinline__ unsigned short f2bf(float f) {
  union { float f; unsigned u; } v; v.f = f;
  return (unsigned short)((v.u + 0x7FFFu + ((v.u >> 16) & 1u)) >> 16); // RNE
}

__device__ __forceinline__ void gload16(const void* g, void* l) {
  __builtin_amdgcn_global_load_lds((glob_uint*)g, (lds_uint*)l, 16, 0, 0);
}

// ---- K0: zero out, convert x -> bf16, zero expert counts --------------------
__global__ void k0_zero_cvt(const float* __restrict__ x,
                            unsigned short* __restrict__ xbf,
                            float* __restrict__ out,
                            int* __restrict__ counts) {
  int i = blockIdx.x * 256 + threadIdx.x;            // 1M float4 groups
  const float4* x4 = (const float4*)x;
  float4 v = x4[i];
  uint2 p;
  p.x = (unsigned)f2bf(v.x) | ((unsigned)f2bf(v.y) << 16);
  p.y = (unsigned)f2bf(v.z) | ((unsigned)f2bf(v.w) << 16);
  ((uint2*)xbf)[i] = p;
  ((float4*)out)[i] = make_float4(0.f, 0.f, 0.f, 0.f);
  if (i < NE) counts[i] = 0;
}

// ---- K1: transpose sub-block + fp32->bf16 -----------------------------------
// src[e][r0+i][c0+j] (i<RW, j<CW) -> dst[e][j][i]  (dst leading dim RW)
__global__ void k1_transpose(const float* __restrict__ src,
                             unsigned short* __restrict__ dst,
                             int Rfull, int Cfull, int r0, int c0,
                             int RW, int CW) {
  __shared__ unsigned short tile[32][33];
  size_t mb = blockIdx.z;
  src += mb * (size_t)Rfull * Cfull;
  dst += mb * (size_t)RW * CW;
  int j  = blockIdx.x * 32 + threadIdx.x;
  int i0 = blockIdx.y * 32;
#pragma unroll
  for (int u = 0; u < 4; u++) {
    int i = i0 + threadIdx.y + u * 8;
    tile[threadIdx.y + u * 8][threadIdx.x] = f2bf(src[(size_t)(r0 + i) * Cfull + c0 + j]);
  }
  __syncthreads();
  int i = i0 + threadIdx.x;
#pragma unroll
  for (int u = 0; u < 4; u++) {
    int jj = blockIdx.x * 32 + threadIdx.y + u * 8;
    dst[(size_t)jj * RW + i] = tile[threadIdx.x][threadIdx.y + u * 8];
  }
}

// ---- K2: router, one wave per token ----------------------------------------
__global__ void k2_router(const float* __restrict__ x,
                          const float* __restrict__ gw,
                          const float* __restrict__ gb,
                          int* __restrict__ topi, float* __restrict__ topw,
                          int* __restrict__ counts) {
  int wid = threadIdx.x >> 6, lane = threadIdx.x & 63;
  int t = blockIdx.x * 4 + wid;
  const float4* x4 = (const float4*)(x + (size_t)t * HID);
  const float4* g4 = (const float4*)gw;
  float acc[8];
#pragma unroll
  for (int e = 0; e < 8; e++) acc[e] = 0.f;
#pragma unroll
  for (int i = 0; i < 4; i++) {
    float4 xv = x4[i * 64 + lane];
    int dbase = (i * 64 + lane) * 4;
    float xs[4] = {xv.x, xv.y, xv.z, xv.w};
#pragma unroll
    for (int j = 0; j < 4; j++) {
      float4 ga  = g4[(dbase + j) * 2];
      float4 gbv = g4[(dbase + j) * 2 + 1];
      acc[0] += xs[j] * ga.x;  acc[1] += xs[j] * ga.y;
      acc[2] += xs[j] * ga.z;  acc[3] += xs[j] * ga.w;
      acc[4] += xs[j] * gbv.x; acc[5] += xs[j] * gbv.y;
      acc[6] += xs[j] * gbv.z; acc[7] += xs[j] * gbv.w;
    }
  }
#pragma unroll
  for (int e = 0; e < 8; e++)
#pragma unroll
    for (int m = 1; m < 64; m <<= 1) acc[e] += __shfl_xor(acc[e], m);
  if (lane == 0) {
    float lg[8];
#pragma unroll
    for (int e = 0; e < 8; e++) lg[e] = acc[e] + gb[e];
    int i0 = 0; float m0 = lg[0];
#pragma unroll
    for (int e = 1; e < 8; e++) if (lg[e] > m0) { m0 = lg[e]; i0 = e; }
    int i1 = -1; float m1 = -1e30f;
#pragma unroll
    for (int e = 0; e < 8; e++) if (e != i0 && lg[e] > m1) { m1 = lg[e]; i1 = e; }
    float w0 = 1.f / (1.f + __expf(m1 - m0));   // == p0/(p0+p1) renormalized
    topi[2 * t] = i0; topi[2 * t + 1] = i1;
    topw[2 * t] = w0; topw[2 * t + 1] = 1.f - w0;
    atomicAdd(&counts[i0], 1);
    atomicAdd(&counts[i1], 1);
  }
}

// ---- K3: segment offsets (128-aligned), tile table, default slots -----------
__global__ void k3_scan(const int* __restrict__ counts, int* offs, int* fill,
                        int* tile_e, int* tile_row,
                        int* sorted_tok, float* sorted_w) {
  if (threadIdx.x == 0) {
    int off = 0, tt = 0;
    for (int e = 0; e < NE; e++) {
      offs[e] = off; fill[e] = 0;
      int nt = (counts[e] + TM - 1) >> 7;
      for (int j = 0; j < nt; j++) { tile_e[tt] = e; tile_row[tt] = off + j * TM; tt++; }
      off += nt * TM;
    }
    for (; tt < MAXT; tt++) { tile_e[tt] = -1; tile_row[tt] = 0; }
  }
  // pad slots: token 0 with weight 0 -> computed normally, contributes nothing
  for (int i = threadIdx.x; i < CAP; i += 256) { sorted_tok[i] = 0; sorted_w[i] = 0.f; }
}

// ---- K4: scatter token ids into expert segments -----------------------------
__global__ void k4_scatter(const int* __restrict__ topi, const float* __restrict__ topw,
                           const int* __restrict__ offs, int* __restrict__ fill,
                           int* __restrict__ sorted_tok, float* __restrict__ sorted_w) {
  int t = blockIdx.x * 256 + threadIdx.x;
#pragma unroll
  for (int k = 0; k < 2; k++) {
    int e = topi[2 * t + k];
    int p = atomicAdd(&fill[e], 1);
    int s = offs[e] + p;
    sorted_tok[s] = t;
    sorted_w[s]   = topw[2 * t + k];
  }
}

// ---- K5: h = silu(X*W1) .* (X*W3), 128x64 tile, dual-B, FC-wide chunk -------
__global__ __launch_bounds__(256) void k5_gemm_h(
    const unsigned short* __restrict__ xbf,
    const unsigned short* __restrict__ w1t,   // [e][f' < FC][d] bf16
    const unsigned short* __restrict__ w3t,   // [e][f' < FC][d] bf16
    unsigned short* __restrict__ h,           // [slot][f' < FC] bf16
    const int* __restrict__ tile_e, const int* __restrict__ tile_row,
    const int* __restrict__ sorted_tok, int FC) {
  __shared__ unsigned short lsA[128 * 32];
  __shared__ unsigned short lsB1[64 * 32];
  __shared__ unsigned short lsB3[64 * 32];

  int tile = blockIdx.x;
  int e = tile_e[tile];
  if (e < 0) return;
  int row0 = tile_row[tile];
  int n0 = blockIdx.y * 64;                   // local f' within chunk
  int tid = threadIdx.x;

  int kc = tid & 3, lr = tid >> 2;            // lr: 0..63
  int tok0 = sorted_tok[row0 + lr];
  int tok1 = sorted_tok[row0 + lr + 64];
  const unsigned short* ga0 = xbf + (size_t)tok0 * HID + kc * 8;
  const unsigned short* ga1 = xbf + (size_t)tok1 * HID + kc * 8;
  const unsigned short* gb1 = w1t + ((size_t)e * FC + n0 + lr) * HID + kc * 8;
  const unsigned short* gb3 = w3t + ((size_t)e * FC + n0 + lr) * HID + kc * 8;
  unsigned short* la0 = lsA  + tid * 8;
  unsigned short* la1 = lsA  + (256 + tid) * 8;
  unsigned short* lb1 = lsB1 + tid * 8;
  unsigned short* lb3 = lsB3 + tid * 8;

  int wid = tid >> 6, lane = tid & 63, lm = lane & 15, q = lane >> 4;
  int wr = wid >> 1, wc = wid & 1;
  const unsigned short* As  = lsA  + (wr * 64 + lm) * 32 + q * 8;
  const unsigned short* B1s = lsB1 + (wc * 32 + lm) * 32 + q * 8;
  const unsigned short* B3s = lsB3 + (wc * 32 + lm) * 32 + q * 8;

  f32x4 acc1[4][2] = {};
  f32x4 acc3[4][2] = {};

#pragma unroll 1
  for (int ks = 0; ks < HID / 32; ks++) {
    __syncthreads();
    int k0 = ks * 32;
    gload16(ga0 + k0, la0);
    gload16(ga1 + k0, la1);
    gload16(gb1 + k0, lb1);
    gload16(gb3 + k0, lb3);
    __syncthreads();   // compiler emits s_waitcnt vmcnt(0) before s_barrier
    bf16x8 a[4], b1f[2], b3f[2];
#pragma unroll
    for (int ti = 0; ti < 4; ti++) a[ti] = *(const bf16x8*)(As + ti * 512);
#pragma unroll
    for (int tj = 0; tj < 2; tj++) {
      b1f[tj] = *(const bf16x8*)(B1s + tj * 512);
      b3f[tj] = *(const bf16x8*)(B3s + tj * 512);
    }
#pragma unroll
    for (int ti = 0; ti < 4; ti++)
#pragma unroll
      for (int tj = 0; tj < 2; tj++) {
        acc1[ti][tj] = __builtin_amdgcn_mfma_f32_16x16x32_bf16(a[ti], b1f[tj], acc1[ti][tj], 0, 0, 0);
        acc3[ti][tj] = __builtin_amdgcn_mfma_f32_16x16x32_bf16(a[ti], b3f[tj], acc3[ti][tj], 0, 0, 0);
      }
  }

#pragma unroll
  for (int ti = 0; ti < 4; ti++)
#pragma unroll
    for (int tj = 0; tj < 2; tj++)
#pragma unroll
      for (int r = 0; r < 4; r++) {
        float v1 = acc1[ti][tj][r];
        float v3 = acc3[ti][tj][r];
        float hv = (v1 / (1.f + __expf(-v1))) * v3;  // silu(v1)*v3
        int grow = row0 + wr * 64 + ti * 16 + q * 4 + r;
        int gcol = n0 + wc * 32 + tj * 16 + lm;
        h[(size_t)grow * FC + gcol] = f2bf(hv);
      }
}

// ---- K6: out += w * (H_chunk * W2t_chunk), 128x128 tile, atomic scatter -----
__global__ __launch_bounds__(256) void k6_gemm_out(
    const unsigned short* __restrict__ h,     // [slot][f' < FC] bf16
    const unsigned short* __restrict__ w2t,   // [e][d][f' < FC] bf16
    float* __restrict__ out,
    const int* __restrict__ tile_e, const int* __restrict__ tile_row,
    const int* __restrict__ sorted_tok, const float* __restrict__ sorted_w,
    int FC) {
  __shared__ unsigned short lsA[128 * 32];
  __shared__ unsigned short lsB[128 * 32];
  __shared__ int   toks[128];
  __shared__ float wts[128];

  int tile = blockIdx.x;
  int e = tile_e[tile];
  if (e < 0) return;
  int row0 = tile_row[tile];
  int n0 = blockIdx.y * 128;
  int tid = threadIdx.x;

  if (tid < 128) { toks[tid] = sorted_tok[row0 + tid]; wts[tid] = sorted_w[row0 + tid]; }

  int kc = tid & 3, lr = tid >> 2;
  const unsigned short* ga0 = h + (size_t)(row0 + lr) * FC + kc * 8;
  const unsigned short* ga1 = h + (size_t)(row0 + lr + 64) * FC + kc * 8;
  const unsigned short* gb0 = w2t + ((size_t)e * HID + n0 + lr) * FC + kc * 8;
  const unsigned short* gb1 = w2t + ((size_t)e * HID + n0 + lr + 64) * FC + kc * 8;
  unsigned short* la0 = lsA + tid * 8;
  unsigned short* la1 = lsA + (256 + tid) * 8;
  unsigned short* lb0 = lsB + tid * 8;
  unsigned short* lb1 = lsB + (256 + tid) * 8;

  int wid = tid >> 6, lane = tid & 63, lm = lane & 15, q = lane >> 4;
  int wr = wid >> 1, wc = wid & 1;
  const unsigned short* As = lsA + (wr * 64 + lm) * 32 + q * 8;
  const unsigned short* Bs = lsB + (wc * 64 + lm) * 32 + q * 8;

  f32x4 acc[4][4] = {};

#pragma unroll 1
  for (int ks = 0; ks < FC / 32; ks++) {
    __syncthreads();
    int k0 = ks * 32;
    gload16(ga0 + k0, la0);
    gload16(ga1 + k0, la1);
    gload16(gb0 + k0, lb0);
    gload16(gb1 + k0, lb1);
    __syncthreads();
    bf16x8 a[4], b[4];
#pragma unroll
    for (int ti = 0; ti < 4; ti++) a[ti] = *(const bf16x8*)(As + ti * 512);
#pragma unroll
    for (int tj = 0; tj < 4; tj++) b[tj] = *(const bf16x8*)(Bs + tj * 512);
#pragma unroll
    for (int ti = 0; ti < 4; ti++)
#pragma unroll
      for (int tj = 0; tj < 4; tj++)
        acc[ti][tj] = __builtin_amdgcn_mfma_f32_16x16x32_bf16(a[ti], b[tj], acc[ti][tj], 0, 0, 0);
  }

#pragma unroll
  for (int ti = 0; ti < 4; ti++)
#pragma unroll
    for (int r = 0; r < 4; r++) {
      int lrow = wr * 64 + ti * 16 + q * 4 + r;
      float wt = wts[lrow];
      if (wt != 0.f) {
        int trow = toks[lrow];
#pragma unroll
        for (int tj = 0; tj < 4; tj++) {
          int gcol = n0 + wc * 64 + tj * 16 + lm;
          atomicAdd(&out[(size_t)trow * HID + gcol], acc[ti][tj][r] * wt);
        }
      }
    }
}

// ---------------------------------------------------------------------------
extern "C" void kernel_launch(void* const* d_in, const int* in_sizes, int n_in,
                              void* d_out, int out_size, void* d_ws, size_t ws_size,
                              hipStream_t stream) {
  const float* x  = (const float*)d_in[0];
  const float* gw = (const float*)d_in[1];
  const float* gb = (const float*)d_in[2];
  const float* w1 = (const float*)d_in[3];
  const float* w3 = (const float*)d_in[4];
  const float* w2 = (const float*)d_in[5];
  float* out = (float*)d_out;

  char* ws = (char*)d_ws;
  // ---- meta block at ws start (144 KB) ----
  int*   counts     = (int*)(ws + 0);          // 8
  int*   fill       = counts + 8;              // 8
  int*   offs       = fill + 8;                // 8
  int*   tile_e     = offs + 8;                // 80
  int*   tile_row   = tile_e + 80;             // 80
  int*   topi       = (int*)(ws + 1024);       // 8192 ints  -> [1024, 33792)
  float* topw       = (float*)(ws + 33792);    // 8192 f32   -> [33792, 66560)
  int*   sorted_tok = (int*)(ws + 66560);      // 9216 ints  -> [66560, 103424)
  float* sorted_w   = (float*)(ws + 103424);   // 9216 f32   -> [103424, 140288)
  // ---- big buffers ----
  unsigned short* xbf = (unsigned short*)(ws + 147456);  // 8 MB -> ends 8536064
  const size_t base = 8536064ull;

  // choose largest FFN chunk FC that fits: 3 weight-chunk buffers + h chunk
  int FC = FFN;
  while (FC > 64) {
    size_t W  = (size_t)NE * FC * HID * 2;
    size_t Hb = (size_t)CAP * FC * 2;
    if (base + 3 * W + Hb <= ws_size) break;
    FC >>= 1;
  }
  size_t W = (size_t)NE * FC * HID * 2;
  unsigned short* w1t  = (unsigned short*)(ws + base);
  unsigned short* w3t  = (unsigned short*)(ws + base + W);
  unsigned short* w2t  = (unsigned short*)(ws + base + 2 * W);
  unsigned short* hbuf = (unsigned short*)(ws + base + 3 * W);
  int nc = FFN / FC;

  k0_zero_cvt<<<4096, 256, 0, stream>>>(x, xbf, out, counts);
  k2_router<<<1024, 256, 0, stream>>>(x, gw, gb, topi, topw, counts);
  k3_scan<<<1, 256, 0, stream>>>(counts, offs, fill, tile_e, tile_row, sorted_tok, sorted_w);
  k4_scatter<<<16, 256, 0, stream>>>(topi, topw, offs, fill, sorted_tok, sorted_w);

  for (int c = 0; c < nc; c++) {
    int c0 = c * FC;
    // w1[e][d][f], take cols chunk -> w1t[e][f'][d]
    k1_transpose<<<dim3(FC / 32, HID / 32, NE), dim3(32, 8), 0, stream>>>(
        w1, w1t, HID, FFN, 0, c0, HID, FC);
    k1_transpose<<<dim3(FC / 32, HID / 32, NE), dim3(32, 8), 0, stream>>>(
        w3, w3t, HID, FFN, 0, c0, HID, FC);
    // w2[e][f][d], take rows chunk -> w2t[e][d][f']
    k1_transpose<<<dim3(HID / 32, FC / 32, NE), dim3(32, 8), 0, stream>>>(
        w2, w2t, FFN, HID, c0, 0, FC, HID);
    k5_gemm_h<<<dim3(MAXT, FC / 64), 256, 0, stream>>>(
        xbf, w1t, w3t, hbuf, tile_e, tile_row, sorted_tok, FC);
    k6_gemm_out<<<dim3(MAXT, HID / 128), 256, 0, stream>>>(
        hbuf, w2t, out, tile_e, tile_row, sorted_tok, sorted_w, FC);
  }
}

// Round 3
// 939.379 us; speedup vs baseline: 1.0101x; 1.0101x over previous
//
#include <hip/hip_runtime.h>

// ---------------------------------------------------------------------------
// BlockSparseMoE: T=4096 tokens, HID=1024, FFN=4096, E=8, top-2, fp32 in/out.
// route (fp32) -> permute tokens into 128-aligned expert segments -> bf16 MFMA
// grouped GEMMs (16x16x32) with global_load_lds(16B) staging.
// R3: vectorized 64x64 transposes (16B both sides); XOR bank swizzle on GEMM
// LDS fragments (global-source side, since global_load_lds LDS dst is fixed).
// ---------------------------------------------------------------------------

#define NTOK 4096
#define HID  1024
#define FFN  4096
#define NE   8
#define TM   128
#define CAP  9216   // max padded slots: 64*128 + 7*128 = 9088 < 9216
#define MAXT 72     // max m-tiles: 64 + 7 = 71 < 72

typedef __bf16 bf16x8 __attribute__((ext_vector_type(8)));
typedef float  f32x4  __attribute__((ext_vector_type(4)));

typedef __attribute__((address_space(3))) unsigned int       lds_uint;
typedef const __attribute__((address_space(1))) unsigned int glob_uint;

__device__ __forceinline__ unsigned short f2bf(float f) {
  union { float f; unsigned u; } v; v.f = f;
  return (unsigned short)((v.u + 0x7FFFu + ((v.u >> 16) & 1u)) >> 16); // RNE
}

__device__ __forceinline__ void gload16(const void* g, void* l) {
  __builtin_amdgcn_global_load_lds((glob_uint*)g, (lds_uint*)l, 16, 0, 0);
}

// ---- K0: zero out, convert x -> bf16, zero expert counts --------------------
__global__ void k0_zero_cvt(const float* __restrict__ x,
                            unsigned short* __restrict__ xbf,
                            float* __restrict__ out,
                            int* __restrict__ counts) {
  int i = blockIdx.x * 256 + threadIdx.x;
  const float4* x4 = (const float4*)x;
  float4 v = x4[i];
  uint2 p;
  p.x = (unsigned)f2bf(v.x) | ((unsigned)f2bf(v.y) << 16);
  p.y = (unsigned)f2bf(v.z) | ((unsigned)f2bf(v.w) << 16);
  ((uint2*)xbf)[i] = p;
  ((float4*)out)[i] = make_float4(0.f, 0.f, 0.f, 0.f);
  if (i < NE) counts[i] = 0;
}

// ---- K1: vectorized 64x64 transpose + fp32->bf16 ----------------------------
// Region of src (Rfull x Cfull per matrix): rows [rg0, rg0+RW), cols [cg0,
// cg0+CW). dst is chunk-local [CW][RW] bf16 per matrix. grid.z picks matrix:
// z<8 -> (s0,d0) expert z, else (s1,d1) expert z-8.
__global__ __launch_bounds__(256) void k1_transpose(
    const float* __restrict__ s0, unsigned short* __restrict__ d0,
    const float* __restrict__ s1, unsigned short* __restrict__ d1,
    int Rfull, int Cfull, int rg0, int cg0, int RW, int CW) {
  __shared__ unsigned short tile[64 * 72];   // pitch 72 (144B): breaks read conflicts
  int z = blockIdx.z;
  const float* src = (z < 8 ? s0 : s1) + (size_t)(z & 7) * Rfull * Cfull;
  unsigned short* dst = (z < 8 ? d0 : d1) + (size_t)(z & 7) * RW * CW;
  int c0 = blockIdx.x * 64;   // local col tile
  int r0 = blockIdx.y * 64;   // local row tile
  int t = threadIdx.x;
  int q = t >> 4, p = t & 15;

  // load 4x4 block at (r0+4q, c0+4p): 4 float4 rows, 16B/lane coalesced
  const float4* s4 = (const float4*)(src + (size_t)(rg0 + r0 + 4 * q) * Cfull
                                     + cg0 + c0) + p;
  unsigned short v[4][4];
#pragma unroll
  for (int u = 0; u < 4; u++) {
    float4 xv = s4[(size_t)u * (Cfull >> 2)];
    v[u][0] = f2bf(xv.x); v[u][1] = f2bf(xv.y);
    v[u][2] = f2bf(xv.z); v[u][3] = f2bf(xv.w);
  }
  // register transpose -> 4x ds_write_b64: tile[col][row0..row0+3]
#pragma unroll
  for (int j = 0; j < 4; j++) {
    ushort4 w = make_ushort4(v[0][j], v[1][j], v[2][j], v[3][j]);
    *(ushort4*)&tile[(4 * p + j) * 72 + 4 * q] = w;
  }
  __syncthreads();
  // store: 16B/lane, 8 lanes cover one dst row (128B), b128 LDS reads
  int b = t & 7;
#pragma unroll
  for (int vi = 0; vi < 2; vi++) {
    int c = (t >> 3) + 32 * vi;                       // 0..63
    uint4 w = *(const uint4*)&tile[c * 72 + 8 * b];
    *(uint4*)(dst + (size_t)(c0 + c) * RW + r0 + 8 * b) = w;
  }
}

// ---- K2: router, one wave per token ----------------------------------------
__global__ void k2_router(const float* __restrict__ x,
                          const float* __restrict__ gw,
                          const float* __restrict__ gb,
                          int* __restrict__ topi, float* __restrict__ topw,
                          int* __restrict__ counts) {
  int wid = threadIdx.x >> 6, lane = threadIdx.x & 63;
  int t = blockIdx.x * 4 + wid;
  const float4* x4 = (const float4*)(x + (size_t)t * HID);
  const float4* g4 = (const float4*)gw;
  float acc[8];
#pragma unroll
  for (int e = 0; e < 8; e++) acc[e] = 0.f;
#pragma unroll
  for (int i = 0; i < 4; i++) {
    float4 xv = x4[i * 64 + lane];
    int dbase = (i * 64 + lane) * 4;
    float xs[4] = {xv.x, xv.y, xv.z, xv.w};
#pragma unroll
    for (int j = 0; j < 4; j++) {
      float4 ga  = g4[(dbase + j) * 2];
      float4 gbv = g4[(dbase + j) * 2 + 1];
      acc[0] += xs[j] * ga.x;  acc[1] += xs[j] * ga.y;
      acc[2] += xs[j] * ga.z;  acc[3] += xs[j] * ga.w;
      acc[4] += xs[j] * gbv.x; acc[5] += xs[j] * gbv.y;
      acc[6] += xs[j] * gbv.z; acc[7] += xs[j] * gbv.w;
    }
  }
#pragma unroll
  for (int e = 0; e < 8; e++)
#pragma unroll
    for (int m = 1; m < 64; m <<= 1) acc[e] += __shfl_xor(acc[e], m);
  if (lane == 0) {
    float lg[8];
#pragma unroll
    for (int e = 0; e < 8; e++) lg[e] = acc[e] + gb[e];
    int i0 = 0; float m0 = lg[0];
#pragma unroll
    for (int e = 1; e < 8; e++) if (lg[e] > m0) { m0 = lg[e]; i0 = e; }
    int i1 = -1; float m1 = -1e30f;
#pragma unroll
    for (int e = 0; e < 8; e++) if (e != i0 && lg[e] > m1) { m1 = lg[e]; i1 = e; }
    float w0 = 1.f / (1.f + __expf(m1 - m0));   // == p0/(p0+p1) renormalized
    topi[2 * t] = i0; topi[2 * t + 1] = i1;
    topw[2 * t] = w0; topw[2 * t + 1] = 1.f - w0;
    atomicAdd(&counts[i0], 1);
    atomicAdd(&counts[i1], 1);
  }
}

// ---- K3: segment offsets (128-aligned), tile table, default slots -----------
__global__ void k3_scan(const int* __restrict__ counts, int* offs, int* fill,
                        int* tile_e, int* tile_row,
                        int* sorted_tok, float* sorted_w) {
  if (threadIdx.x == 0) {
    int off = 0, tt = 0;
    for (int e = 0; e < NE; e++) {
      offs[e] = off; fill[e] = 0;
      int nt = (counts[e] + TM - 1) >> 7;
      for (int j = 0; j < nt; j++) { tile_e[tt] = e; tile_row[tt] = off + j * TM; tt++; }
      off += nt * TM;
    }
    for (; tt < MAXT; tt++) { tile_e[tt] = -1; tile_row[tt] = 0; }
  }
  for (int i = threadIdx.x; i < CAP; i += 256) { sorted_tok[i] = 0; sorted_w[i] = 0.f; }
}

// ---- K4: scatter token ids into expert segments -----------------------------
__global__ void k4_scatter(const int* __restrict__ topi, const float* __restrict__ topw,
                           const int* __restrict__ offs, int* __restrict__ fill,
                           int* __restrict__ sorted_tok, float* __restrict__ sorted_w) {
  int t = blockIdx.x * 256 + threadIdx.x;
#pragma unroll
  for (int k = 0; k < 2; k++) {
    int e = topi[2 * t + k];
    int p = atomicAdd(&fill[e], 1);
    int s = offs[e] + p;
    sorted_tok[s] = t;
    sorted_w[s]   = topw[2 * t + k];
  }
}

// Bank swizzle: LDS phys column kc of row r holds logical k-group
// kc ^ ((r>>1)&3). Loader bakes it into the GLOBAL source address (LDS dst of
// global_load_lds is fixed lane-contiguous); fragment readers address phys
// column q ^ ((lm>>1)&3). Makes every b128 quarter-wave 2-way (free).

// ---- K5: h = silu(X*W1) .* (X*W3), 128x64 tile, dual-B, FC-wide chunk -------
template<int CFC>
__global__ __launch_bounds__(256) void k5_gemm_h(
    const unsigned short* __restrict__ xbf,
    const unsigned short* __restrict__ w1t,   // [e][f'][d] bf16
    const unsigned short* __restrict__ w3t,
    unsigned short* __restrict__ h,           // [slot][f'] bf16
    const int* __restrict__ tile_e, const int* __restrict__ tile_row,
    const int* __restrict__ sorted_tok, int FCdyn) {
  const int FC = CFC ? CFC : FCdyn;
  __shared__ unsigned short lsA[128 * 32];
  __shared__ unsigned short lsB1[64 * 32];
  __shared__ unsigned short lsB3[64 * 32];

  int tile = blockIdx.x;
  int e = tile_e[tile];
  if (e < 0) return;
  int row0 = tile_row[tile];
  int n0 = blockIdx.y * 64;
  int tid = threadIdx.x;

  int kc = tid & 3, lr = tid >> 2;
  int g = (kc ^ ((lr >> 1) & 3)) * 8;           // swizzled logical k-group
  int tok0 = sorted_tok[row0 + lr];
  int tok1 = sorted_tok[row0 + lr + 64];
  const unsigned short* ga0 = xbf + (size_t)tok0 * HID + g;
  const unsigned short* ga1 = xbf + (size_t)tok1 * HID + g;   // ((lr+64)>>1)&3 == (lr>>1)&3
  const unsigned short* gb1 = w1t + ((size_t)e * FC + n0 + lr) * HID + g;
  const unsigned short* gb3 = w3t + ((size_t)e * FC + n0 + lr) * HID + g;
  unsigned short* la0 = lsA  + tid * 8;
  unsigned short* la1 = lsA  + (256 + tid) * 8;
  unsigned short* lb1 = lsB1 + tid * 8;
  unsigned short* lb3 = lsB3 + tid * 8;

  int wid = tid >> 6, lane = tid & 63, lm = lane & 15, q = lane >> 4;
  int wr = wid >> 1, wc = wid & 1;
  int qs = (q ^ ((lm >> 1) & 3)) * 8;           // phys column for logical q
  const unsigned short* As  = lsA  + (wr * 64 + lm) * 32 + qs;
  const unsigned short* B1s = lsB1 + (wc * 32 + lm) * 32 + qs;
  const unsigned short* B3s = lsB3 + (wc * 32 + lm) * 32 + qs;

  f32x4 acc1[4][2] = {};
  f32x4 acc3[4][2] = {};

#pragma unroll 1
  for (int ks = 0; ks < HID / 32; ks++) {
    __syncthreads();
    int k0 = ks * 32;
    gload16(ga0 + k0, la0);
    gload16(ga1 + k0, la1);
    gload16(gb1 + k0, lb1);
    gload16(gb3 + k0, lb3);
    __syncthreads();
    bf16x8 a[4], b1f[2], b3f[2];
#pragma unroll
    for (int ti = 0; ti < 4; ti++) a[ti] = *(const bf16x8*)(As + ti * 512);
#pragma unroll
    for (int tj = 0; tj < 2; tj++) {
      b1f[tj] = *(const bf16x8*)(B1s + tj * 512);
      b3f[tj] = *(const bf16x8*)(B3s + tj * 512);
    }
#pragma unroll
    for (int ti = 0; ti < 4; ti++)
#pragma unroll
      for (int tj = 0; tj < 2; tj++) {
        acc1[ti][tj] = __builtin_amdgcn_mfma_f32_16x16x32_bf16(a[ti], b1f[tj], acc1[ti][tj], 0, 0, 0);
        acc3[ti][tj] = __builtin_amdgcn_mfma_f32_16x16x32_bf16(a[ti], b3f[tj], acc3[ti][tj], 0, 0, 0);
      }
  }

#pragma unroll
  for (int ti = 0; ti < 4; ti++)
#pragma unroll
    for (int tj = 0; tj < 2; tj++)
#pragma unroll
      for (int r = 0; r < 4; r++) {
        float v1 = acc1[ti][tj][r];
        float v3 = acc3[ti][tj][r];
        float hv = (v1 / (1.f + __expf(-v1))) * v3;
        int grow = row0 + wr * 64 + ti * 16 + q * 4 + r;
        int gcol = n0 + wc * 32 + tj * 16 + lm;
        h[(size_t)grow * FC + gcol] = f2bf(hv);
      }
}

// ---- K6: out += w * (H_chunk * W2t_chunk), 128x128 tile, atomic scatter -----
template<int CFC>
__global__ __launch_bounds__(256) void k6_gemm_out(
    const unsigned short* __restrict__ h,     // [slot][f'] bf16
    const unsigned short* __restrict__ w2t,   // [e][d][f'] bf16
    float* __restrict__ out,
    const int* __restrict__ tile_e, const int* __restrict__ tile_row,
    const int* __restrict__ sorted_tok, const float* __restrict__ sorted_w,
    int FCdyn) {
  const int FC = CFC ? CFC : FCdyn;
  __shared__ unsigned short lsA[128 * 32];
  __shared__ unsigned short lsB[128 * 32];
  __shared__ int   toks[128];
  __shared__ float wts[128];

  int tile = blockIdx.x;
  int e = tile_e[tile];
  if (e < 0) return;
  int row0 = tile_row[tile];
  int n0 = blockIdx.y * 128;
  int tid = threadIdx.x;

  if (tid < 128) { toks[tid] = sorted_tok[row0 + tid]; wts[tid] = sorted_w[row0 + tid]; }

  int kc = tid & 3, lr = tid >> 2;
  int g = (kc ^ ((lr >> 1) & 3)) * 8;
  const unsigned short* ga0 = h + (size_t)(row0 + lr) * FC + g;
  const unsigned short* ga1 = h + (size_t)(row0 + lr + 64) * FC + g;
  const unsigned short* gb0 = w2t + ((size_t)e * HID + n0 + lr) * FC + g;
  const unsigned short* gb1 = w2t + ((size_t)e * HID + n0 + lr + 64) * FC + g;
  unsigned short* la0 = lsA + tid * 8;
  unsigned short* la1 = lsA + (256 + tid) * 8;
  unsigned short* lb0 = lsB + tid * 8;
  unsigned short* lb1 = lsB + (256 + tid) * 8;

  int wid = tid >> 6, lane = tid & 63, lm = lane & 15, q = lane >> 4;
  int wr = wid >> 1, wc = wid & 1;
  int qs = (q ^ ((lm >> 1) & 3)) * 8;
  const unsigned short* As = lsA + (wr * 64 + lm) * 32 + qs;
  const unsigned short* Bs = lsB + (wc * 64 + lm) * 32 + qs;

  f32x4 acc[4][4] = {};

#pragma unroll 1
  for (int ks = 0; ks < FC / 32; ks++) {
    __syncthreads();
    int k0 = ks * 32;
    gload16(ga0 + k0, la0);
    gload16(ga1 + k0, la1);
    gload16(gb0 + k0, lb0);
    gload16(gb1 + k0, lb1);
    __syncthreads();
    bf16x8 a[4], b[4];
#pragma unroll
    for (int ti = 0; ti < 4; ti++) a[ti] = *(const bf16x8*)(As + ti * 512);
#pragma unroll
    for (int tj = 0; tj < 4; tj++) b[tj] = *(const bf16x8*)(Bs + tj * 512);
#pragma unroll
    for (int ti = 0; ti < 4; ti++)
#pragma unroll
      for (int tj = 0; tj < 4; tj++)
        acc[ti][tj] = __builtin_amdgcn_mfma_f32_16x16x32_bf16(a[ti], b[tj], acc[ti][tj], 0, 0, 0);
  }

#pragma unroll
  for (int ti = 0; ti < 4; ti++)
#pragma unroll
    for (int r = 0; r < 4; r++) {
      int lrow = wr * 64 + ti * 16 + q * 4 + r;
      float wt = wts[lrow];
      if (wt != 0.f) {
        int trow = toks[lrow];
#pragma unroll
        for (int tj = 0; tj < 4; tj++) {
          int gcol = n0 + wc * 64 + tj * 16 + lm;
          atomicAdd(&out[(size_t)trow * HID + gcol], acc[ti][tj][r] * wt);
        }
      }
    }
}

// ---------------------------------------------------------------------------
extern "C" void kernel_launch(void* const* d_in, const int* in_sizes, int n_in,
                              void* d_out, int out_size, void* d_ws, size_t ws_size,
                              hipStream_t stream) {
  const float* x  = (const float*)d_in[0];
  const float* gw = (const float*)d_in[1];
  const float* gb = (const float*)d_in[2];
  const float* w1 = (const float*)d_in[3];
  const float* w3 = (const float*)d_in[4];
  const float* w2 = (const float*)d_in[5];
  float* out = (float*)d_out;

  char* ws = (char*)d_ws;
  int*   counts     = (int*)(ws + 0);
  int*   fill       = counts + 8;
  int*   offs       = fill + 8;
  int*   tile_e     = offs + 8;
  int*   tile_row   = tile_e + 80;
  int*   topi       = (int*)(ws + 1024);
  float* topw       = (float*)(ws + 33792);
  int*   sorted_tok = (int*)(ws + 66560);
  float* sorted_w   = (float*)(ws + 103424);
  unsigned short* xbf = (unsigned short*)(ws + 147456);
  const size_t base = 8536064ull;

  int FC = FFN;
  while (FC > 64) {
    size_t W  = (size_t)NE * FC * HID * 2;
    size_t Hb = (size_t)CAP * FC * 2;
    if (base + 3 * W + Hb <= ws_size) break;
    FC >>= 1;
  }
  size_t W = (size_t)NE * FC * HID * 2;
  unsigned short* w1t  = (unsigned short*)(ws + base);
  unsigned short* w3t  = (unsigned short*)(ws + base + W);
  unsigned short* w2t  = (unsigned short*)(ws + base + 2 * W);
  unsigned short* hbuf = (unsigned short*)(ws + base + 3 * W);
  int nc = FFN / FC;

  k0_zero_cvt<<<4096, 256, 0, stream>>>(x, xbf, out, counts);
  k2_router<<<1024, 256, 0, stream>>>(x, gw, gb, topi, topw, counts);
  k3_scan<<<1, 256, 0, stream>>>(counts, offs, fill, tile_e, tile_row, sorted_tok, sorted_w);
  k4_scatter<<<16, 256, 0, stream>>>(topi, topw, offs, fill, sorted_tok, sorted_w);

  for (int c = 0; c < nc; c++) {
    int c0 = c * FC;
    // w1/w3 [e][HID][FFN] cols chunk -> [e][FC][HID] (fused, grid.z=16)
    k1_transpose<<<dim3(FC / 64, HID / 64, 16), 256, 0, stream>>>(
        w1, w1t, w3, w3t, HID, FFN, 0, c0, HID, FC);
    // w2 [e][FFN][HID] rows chunk -> [e][HID][FC]
    k1_transpose<<<dim3(HID / 64, FC / 64, 8), 256, 0, stream>>>(
        w2, w2t, nullptr, nullptr, FFN, HID, c0, 0, FC, HID);
    if (FC == 4096) {
      k5_gemm_h<4096><<<dim3(MAXT, FC / 64), 256, 0, stream>>>(
          xbf, w1t, w3t, hbuf, tile_e, tile_row, sorted_tok, FC);
      k6_gemm_out<4096><<<dim3(MAXT, HID / 128), 256, 0, stream>>>(
          hbuf, w2t, out, tile_e, tile_row, sorted_tok, sorted_w, FC);
    } else if (FC == 2048) {
      k5_gemm_h<2048><<<dim3(MAXT, FC / 64), 256, 0, stream>>>(
          xbf, w1t, w3t, hbuf, tile_e, tile_row, sorted_tok, FC);
      k6_gemm_out<2048><<<dim3(MAXT, HID / 128), 256, 0, stream>>>(
          hbuf, w2t, out, tile_e, tile_row, sorted_tok, sorted_w, FC);
    } else if (FC == 1024) {
      k5_gemm_h<1024><<<dim3(MAXT, FC / 64), 256, 0, stream>>>(
          xbf, w1t, w3t, hbuf, tile_e, tile_row, sorted_tok, FC);
      k6_gemm_out<1024><<<dim3(MAXT, HID / 128), 256, 0, stream>>>(
          hbuf, w2t, out, tile_e, tile_row, sorted_tok, sorted_w, FC);
    } else {
      k5_gemm_h<0><<<dim3(MAXT, FC / 64), 256, 0, stream>>>(
          xbf, w1t, w3t, hbuf, tile_e, tile_row, sorted_tok, FC);
      k6_gemm_out<0><<<dim3(MAXT, HID / 128), 256, 0, stream>>>(
          hbuf, w2t, out, tile_e, tile_row, sorted_tok, sorted_w, FC);
    }
  }
}